// Round 8
// baseline (62.878 us; speedup 1.0000x reference)
//
#include <hip/hip_runtime.h>
#include <hip/hip_bf16.h>
#include <math.h>

#define NN 1000
#define DD 128
#define HH 128
#define H2 64
#define KK 10
#define EE 500000
#define LN_EPS 1e-5f

typedef float v2f __attribute__((ext_vector_type(2)));
typedef unsigned int uint;

// output offsets (floats)
#define OFF_LOGITS  0
#define OFF_PROBS   10000
#define OFF_SCORES  20000
#define OFF_MATRIX  520000
#define OFF_CENTERS 1520000
#define OFF_PROTO   1521280

__device__ __forceinline__ uint pack_bf16x2(float a, float b) {
  uint ua = __float_as_uint(a);
  uint ub = __float_as_uint(b);
  ua = (ua + 0x7FFFu + ((ua >> 16) & 1u)) >> 16;       // RNE
  ub = (ub + 0x7FFFu + ((ub >> 16) & 1u)) & 0xFFFF0000u;
  return ua | ub;
}

__device__ __forceinline__ v2f unpk(uint u) {
  v2f r;
  r.x = __uint_as_float(u << 16);
  r.y = __uint_as_float(u & 0xFFFF0000u);
  return r;
}

// ===== Kernel 1: proj blocks (0..499, 2 rows each) + cluster (500..999) ====
__global__ __launch_bounds__(256) void k1_split(
    const float* __restrict__ x,
    const float* __restrict__ w1, const float* __restrict__ b1,
    const float* __restrict__ g1, const float* __restrict__ be1,
    const float* __restrict__ w2, const float* __restrict__ b2,
    const float* __restrict__ g2, const float* __restrict__ be2,
    const float* __restrict__ w3, const float* __restrict__ b3,
    const float* __restrict__ cw1, const float* __restrict__ cb1,
    float* __restrict__ out_logits, float* __restrict__ out_probs,
    float* __restrict__ hi, float* __restrict__ hjbT,
    float* __restrict__ Srow, float* __restrict__ Qrow,
    float* __restrict__ Tcol, float* __restrict__ Rcol) {
  const int b = blockIdx.x;
  const int t = threadIdx.x;

  if (b < NN / 2) {
    // ------------- proj block: rows r0, r0+1; weight cols shared ----------
    __shared__ float sx2[2][DD];
    __shared__ float red[16];
    const int r0 = 2 * b;
    if (t < 64) {
      const int rr = t >> 5, c4 = t & 31;
      *(float4*)&sx2[rr][4 * c4] = *(const float4*)&x[(r0 + rr) * DD + 4 * c4];
    }
    __syncthreads();

    const int col = t & 127;
    const float* wcol = (t < 128) ? (cw1 + col) : (cw1 + DD * HH + col);
    float p00 = 0.f, p01 = 0.f, p10 = 0.f, p11 = 0.f;
#pragma unroll 8
    for (int d = 0; d < DD; d += 2) {
      const float w0 = wcol[d * HH];
      const float w1_ = wcol[(d + 1) * HH];
      const float2 x0 = *(const float2*)&sx2[0][d];
      const float2 x1 = *(const float2*)&sx2[1][d];
      p00 = fmaf(x0.x, w0, p00); p01 = fmaf(x0.y, w1_, p01);
      p10 = fmaf(x1.x, w0, p10); p11 = fmaf(x1.y, w1_, p11);
    }
    float acc0 = p00 + p01, acc1 = p10 + p11;
    if (t >= 128) { const float cb_ = cb1[col]; acc0 += cb_; acc1 += cb_; }
    if (t < 128) {
      hi[(r0 + 0) * HH + col] = acc0;
      hi[(r0 + 1) * HH + col] = acc1;
    } else {
      *(float2*)&hjbT[col * NN + r0] = (float2){acc0, acc1};
    }
    // stats for both rows
    float s0 = acc0, q0 = acc0 * acc0, s1 = acc1, q1 = acc1 * acc1;
#pragma unroll
    for (int o = 1; o < 64; o <<= 1) {
      s0 += __shfl_xor(s0, o, 64); q0 += __shfl_xor(q0, o, 64);
      s1 += __shfl_xor(s1, o, 64); q1 += __shfl_xor(q1, o, 64);
    }
    const int wid = t >> 6;
    if ((t & 63) == 0) {
      red[wid * 4 + 0] = s0; red[wid * 4 + 1] = q0;
      red[wid * 4 + 2] = s1; red[wid * 4 + 3] = q1;
    }
    __syncthreads();
    if (t == 0) {
      Srow[r0] = red[0] + red[4];  Qrow[r0] = red[1] + red[5];
      Srow[r0 + 1] = red[2] + red[6]; Qrow[r0 + 1] = red[3] + red[7];
    }
    if (t == 128) {
      Tcol[r0] = red[8] + red[12];  Rcol[r0] = red[9] + red[13];
      Tcol[r0 + 1] = red[10] + red[14]; Rcol[r0 + 1] = red[11] + red[15];
    }
  } else {
    // ---------------- cluster block: rows r0, r0+1 ----------------
    __shared__ float sx2[2][DD];
    __shared__ float shh[2][HH];
    __shared__ float sh2[2][H2];
    __shared__ float redc[8];
    __shared__ float slg2[2][16];
    const int m = b - NN / 2;
    const int r0 = 2 * m;
    if (t < 32)      *(float4*)&sx2[0][4 * t] = *(const float4*)&x[r0 * DD + 4 * t];
    else if (t < 64) *(float4*)&sx2[1][4 * (t - 32)] =
                         *(const float4*)&x[(r0 + 1) * DD + 4 * (t - 32)];
    __syncthreads();

    const int row = t >> 7;
    const int col = t & 127;

    // ---- layer 1 ----
    float a0 = 0.f, a1 = 0.f, a2 = 0.f, a3 = 0.f;
    const float* wc = w1 + col;
#pragma unroll 8
    for (int d = 0; d < DD; d += 4) {
      const float4 xv = *(const float4*)&sx2[row][d];
      a0 = fmaf(xv.x, wc[(d + 0) * HH], a0);
      a1 = fmaf(xv.y, wc[(d + 1) * HH], a1);
      a2 = fmaf(xv.z, wc[(d + 2) * HH], a2);
      a3 = fmaf(xv.w, wc[(d + 3) * HH], a3);
    }
    float acc = (a0 + a1) + (a2 + a3) + b1[col];
    {
      float s = acc, q = acc * acc;
#pragma unroll
      for (int o = 1; o < 64; o <<= 1) {
        s += __shfl_xor(s, o, 64);
        q += __shfl_xor(q, o, 64);
      }
      const int wid = t >> 6;
      if ((t & 63) == 0) { redc[wid * 2] = s; redc[wid * 2 + 1] = q; }
    }
    __syncthreads();
    {
      const float s = redc[4 * row] + redc[4 * row + 2];
      const float q = redc[4 * row + 1] + redc[4 * row + 3];
      const float mn = s * (1.0f / HH);
      const float var = q * (1.0f / HH) - mn * mn;
      const float rs = rsqrtf(var + LN_EPS);
      shh[row][col] = fmaxf(fmaf((acc - mn) * rs, g1[col], be1[col]), 0.0f);
    }
    __syncthreads();

    // ---- layer 2 ----
    if (t < 128) {
      const int rw = t >> 6, c2 = t & 63;
      float b0 = 0.f, b1_ = 0.f, b2_ = 0.f, b3_ = 0.f;
      const float* w2c = w2 + c2;
#pragma unroll 8
      for (int d = 0; d < HH; d += 4) {
        const float4 hv = *(const float4*)&shh[rw][d];
        b0 = fmaf(hv.x, w2c[(d + 0) * H2], b0);
        b1_ = fmaf(hv.y, w2c[(d + 1) * H2], b1_);
        b2_ = fmaf(hv.z, w2c[(d + 2) * H2], b2_);
        b3_ = fmaf(hv.w, w2c[(d + 3) * H2], b3_);
      }
      float av = (b0 + b1_) + (b2_ + b3_) + b2[c2];
      float s2 = av, q2 = av * av;
#pragma unroll
      for (int o = 1; o < 64; o <<= 1) {
        s2 += __shfl_xor(s2, o, 64);
        q2 += __shfl_xor(q2, o, 64);
      }
      const float m2 = s2 * (1.0f / H2);
      const float var2 = q2 * (1.0f / H2) - m2 * m2;
      const float rs2 = rsqrtf(var2 + LN_EPS);
      sh2[rw][c2] = fmaxf(fmaf((av - m2) * rs2, g2[c2], be2[c2]), 0.0f);
    }
    __syncthreads();

    // ---- layer 3 + softmax ----
    if (t < 32) {
      const int rw = t >> 4, k = t & 15;
      if (k < KK) {
        float a3_ = b3[k];
#pragma unroll
        for (int d = 0; d < H2; ++d) a3_ = fmaf(sh2[rw][d], w3[d * KK + k], a3_);
        out_logits[(r0 + rw) * KK + k] = a3_;
        slg2[rw][k] = a3_;
      }
    }
    __syncthreads();
    if (t < 32) {
      const int rw = t >> 4, k = t & 15;
      if (k < KK) {
        float mx = -1e30f;
#pragma unroll
        for (int i = 0; i < KK; ++i) mx = fmaxf(mx, slg2[rw][i]);
        float den = 0.0f;
#pragma unroll
        for (int i = 0; i < KK; ++i) den += expf(slg2[rw][i] - mx);
        out_probs[(r0 + rw) * KK + k] = expf(slg2[rw][k] - mx) / den;
      }
    }
  }
}

// ------- Kernel 2: cluster-center partials (125 blocks x 8 nodes) ----------
#define NCB 8
#define NPB 125

__global__ __launch_bounds__(128) void k_centers_part(
    const float* __restrict__ x, const float* __restrict__ probs,
    float* __restrict__ pc, float* __restrict__ pw) {
  __shared__ float sp[NCB * KK];
  const int b = blockIdx.x;
  const int t = threadIdx.x;
  const int n0 = b * NCB;
  if (t < NCB * KK) sp[t] = probs[n0 * KK + t];
  __syncthreads();
  float acc[KK];
#pragma unroll
  for (int k = 0; k < KK; ++k) acc[k] = 0.0f;
#pragma unroll
  for (int nn = 0; nn < NCB; ++nn) {
    const float xv = x[(n0 + nn) * DD + t];
#pragma unroll
    for (int k = 0; k < KK; ++k) acc[k] = fmaf(sp[nn * KK + k], xv, acc[k]);
  }
#pragma unroll
  for (int k = 0; k < KK; ++k) pc[b * (KK * DD) + k * DD + t] = acc[k];
  if (t < KK) {
    float s = 0.0f;
#pragma unroll
    for (int nn = 0; nn < NCB; ++nn) s += sp[nn * KK + t];
    pw[b * 16 + t] = s;
  }
}

// ===== Kernel 3: dense matrix — 64x32 tile, 4x2/thread, bf16 LDS ==========
#define TI 64
#define TJ 32
#define SA_STR 66    // uints per A row (64 h-pairs + 2 pad)
#define SB_STR 132   // uints per B col-pair row (128 + 4 pad; 16B aligned)

__global__ __launch_bounds__(256) void k_matrix(
    const float* __restrict__ hi, const float* __restrict__ hjbT,
    const float* __restrict__ Srow, const float* __restrict__ Qrow,
    const float* __restrict__ Tcol, const float* __restrict__ Rcol,
    const float* __restrict__ cg1, const float* __restrict__ cbe1,
    const float* __restrict__ cw2, const float* __restrict__ cb2,
    float* __restrict__ out_mat) {
  __shared__ uint sa[TI * SA_STR];    // 16.9 KB
  __shared__ uint sb[16 * SB_STR];    // 8.4 KB
  const int t = threadIdx.x;
  const int j0 = blockIdx.x * TJ;
  const int i0 = blockIdx.y * TI;

  // stage A: 64 rows x 64 bf16-pair uints; coalesced float2 reads
#pragma unroll
  for (int it = 0; it < 16; ++it) {
    const int idx = it * 256 + t;
    const int r = idx >> 6, w = idx & 63;
    int gi = i0 + r; if (gi >= NN) gi = NN - 1;
    const float2 av = *(const float2*)&hi[gi * HH + 2 * w];
    sa[r * SA_STR + w] = pack_bf16x2(av.x, av.y);
  }
  // stage B: 16 col-pairs x 128 h (cp-major)
  {
    const int cp = t & 15;
    const int hw = t >> 4;   // 0..15
    const int jc = j0 + 2 * cp;
    const int c0 = (jc < NN) ? jc : NN - 1;
    const int c1 = (jc + 1 < NN) ? jc + 1 : NN - 1;
#pragma unroll
    for (int hb = 0; hb < 8; ++hb) {
      const int h = hb * 16 + hw;
      sb[cp * SB_STR + h] = pack_bf16x2(hjbT[h * NN + c0], hjbT[h * NN + c1]);
    }
  }
  __syncthreads();

  const int tr = t >> 4, tc = t & 15;
  const int ia = 4 * tr;          // 4 rows
  const int gi0 = i0 + ia;
  const int gj0 = j0 + 2 * tc;    // col pair

  // stats
  float Sr[4], Qr[4];
#pragma unroll
  for (int r = 0; r < 4; ++r) {
    const int gi = (gi0 + r < NN) ? gi0 + r : NN - 1;
    Sr[r] = Srow[gi]; Qr[r] = Qrow[gi];
  }
  const int cc0 = (gj0 < NN) ? gj0 : NN - 1;
  const int cc1 = (gj0 + 1 < NN) ? gj0 + 1 : NN - 1;
  const v2f Tc2 = (v2f){Tcol[cc0], Tcol[cc1]};
  const v2f Rc2 = (v2f){Rcol[cc0], Rcol[cc1]};

  // ---- pass 1: dot over h ----
  v2f dt[4];
#pragma unroll
  for (int r = 0; r < 4; ++r) dt[r] = (v2f){0.f, 0.f};

#pragma unroll 2
  for (int h = 0; h < HH; h += 4) {
    const uint4 bu = *(const uint4*)&sb[tc * SB_STR + h];
    const v2f b0 = unpk(bu.x), b1 = unpk(bu.y), b2_ = unpk(bu.z), b3_ = unpk(bu.w);
#pragma unroll
    for (int r = 0; r < 4; ++r) {
      const uint2 au = *(const uint2*)&sa[(ia + r) * SA_STR + (h >> 1)];
      const v2f a01 = unpk(au.x), a23 = unpk(au.y);
      dt[r] += (v2f){a01.x, a01.x} * b0 + (v2f){a01.y, a01.y} * b1
             + (v2f){a23.x, a23.x} * b2_ + (v2f){a23.y, a23.y} * b3_;
    }
  }

  // LN coefficients
  const float inv = 1.0f / HH;
  v2f rrv[4], nmv[4];
#pragma unroll
  for (int r = 0; r < 4; ++r) {
    const v2f mu = (Sr[r] + Tc2) * inv;
    const v2f ev2 = (Qr[r] + Rc2 + 2.0f * dt[r]) * inv;
    const v2f var = ev2 - mu * mu;
    v2f rs;
    rs.x = rsqrtf(var.x + LN_EPS);
    rs.y = rsqrtf(var.y + LN_EPS);
    rrv[r] = rs;
    nmv[r] = -mu * rs;
  }

  // ---- pass 2 ----
  v2f cc[4];
#pragma unroll
  for (int r = 0; r < 4; ++r) cc[r] = (v2f){0.f, 0.f};
  const v2f vzero = (v2f){0.f, 0.f};

#pragma unroll 2
  for (int h = 0; h < HH; h += 4) {
    const uint4 bu = *(const uint4*)&sb[tc * SB_STR + h];
    const v2f b0 = unpk(bu.x), b1 = unpk(bu.y), b2_ = unpk(bu.z), b3_ = unpk(bu.w);
    // uniform -> scalar loads (off the LDS pipe)
    const float4 gq = *(const float4*)&cg1[h];
    const float4 eq = *(const float4*)&cbe1[h];
    const float4 wq = *(const float4*)&cw2[h];
#pragma unroll
    for (int r = 0; r < 4; ++r) {
      const uint2 au = *(const uint2*)&sa[(ia + r) * SA_STR + (h >> 1)];
      const v2f a01 = unpk(au.x), a23 = unpk(au.y);
      v2f z;
      z = ((v2f){a01.x, a01.x} + b0) * rrv[r] + nmv[r];
      z = z * (v2f){gq.x, gq.x} + (v2f){eq.x, eq.x};
      z = __builtin_elementwise_max(z, vzero);
      cc[r] += z * (v2f){wq.x, wq.x};
      z = ((v2f){a01.y, a01.y} + b1) * rrv[r] + nmv[r];
      z = z * (v2f){gq.y, gq.y} + (v2f){eq.y, eq.y};
      z = __builtin_elementwise_max(z, vzero);
      cc[r] += z * (v2f){wq.y, wq.y};
      z = ((v2f){a23.x, a23.x} + b2_) * rrv[r] + nmv[r];
      z = z * (v2f){gq.z, gq.z} + (v2f){eq.z, eq.z};
      z = __builtin_elementwise_max(z, vzero);
      cc[r] += z * (v2f){wq.z, wq.z};
      z = ((v2f){a23.y, a23.y} + b3_) * rrv[r] + nmv[r];
      z = z * (v2f){gq.w, gq.w} + (v2f){eq.w, eq.w};
      z = __builtin_elementwise_max(z, vzero);
      cc[r] += z * (v2f){wq.w, wq.w};
    }
  }

  // ---- epilogue ----
  const float cb = cb2[0];
  if (gj0 < NN) {
#pragma unroll
    for (int r = 0; r < 4; ++r) {
      const int gi = gi0 + r;
      if (gi < NN) {
        float2 o;
        o.x = tanhf(cc[r].x + cb);
        o.y = tanhf(cc[r].y + cb);
        *(float2*)&out_mat[gi * NN + gj0] = o;
      }
    }
  }
}

// ===== Kernel 4: tail — centers finalize (blocks 0-9) + edge gather ========
__global__ __launch_bounds__(256) void k_tail(
    const float* __restrict__ pc, const float* __restrict__ pw,
    const float* __restrict__ proto, const int* __restrict__ ei,
    const float* __restrict__ mat,
    float* __restrict__ out_centers, float* __restrict__ out_proto,
    float* __restrict__ out_scores) {
  const int b = blockIdx.x;
  const int t = threadIdx.x;
  if (b < KK) {
    __shared__ float sred[128];
    const int k = b;
    if (t < 128) sred[t] = (t < NPB) ? pw[t * 16 + k] : 0.0f;
    __syncthreads();
    for (int o = 64; o > 0; o >>= 1) {
      if (t < o) sred[t] += sred[t + o];
      __syncthreads();
    }
    if (t < 128) {
      const float wsum = sred[0] + 1e-8f;
      float acc = 0.0f;
#pragma unroll 5
      for (int bb = 0; bb < NPB; ++bb) acc += pc[bb * (KK * DD) + k * DD + t];
      out_centers[k * DD + t] = acc / wsum;
      out_proto[k * DD + t] = proto[k * DD + t];
    }
  } else {
    const int e = (b - KK) * 256 + t;
    if (e < EE) {
      const int r = ei[e];
      const int c = ei[EE + e];
      out_scores[e] = mat[r * NN + c];
    }
  }
}

extern "C" void kernel_launch(void* const* d_in, const int* in_sizes, int n_in,
                              void* d_out, int out_size, void* d_ws, size_t ws_size,
                              hipStream_t stream) {
  const float* x    = (const float*)d_in[0];
  const int*   ei   = (const int*)d_in[1];
  const float* w1   = (const float*)d_in[2];
  const float* b1   = (const float*)d_in[3];
  const float* g1   = (const float*)d_in[4];
  const float* be1  = (const float*)d_in[5];
  const float* w2   = (const float*)d_in[6];
  const float* b2   = (const float*)d_in[7];
  const float* g2   = (const float*)d_in[8];
  const float* be2  = (const float*)d_in[9];
  const float* w3   = (const float*)d_in[10];
  const float* b3   = (const float*)d_in[11];
  const float* cw1  = (const float*)d_in[12];
  const float* cb1  = (const float*)d_in[13];
  const float* cg1  = (const float*)d_in[14];
  const float* cbe1 = (const float*)d_in[15];
  const float* cw2  = (const float*)d_in[16];
  const float* cb2  = (const float*)d_in[17];
  const float* prot = (const float*)d_in[18];

  float* out        = (float*)d_out;
  float* out_logits = out + OFF_LOGITS;
  float* out_probs  = out + OFF_PROBS;
  float* out_scores = out + OFF_SCORES;
  float* out_mat    = out + OFF_MATRIX;
  float* out_cent   = out + OFF_CENTERS;
  float* out_proto  = out + OFF_PROTO;

  float* hi   = (float*)d_ws;           // NN*HH
  float* hjbT = hi + NN * HH;           // HH*NN
  float* Srow = hjbT + NN * HH;         // NN
  float* Qrow = Srow + NN;              // NN
  float* Tcol = Qrow + NN;              // NN
  float* Rcol = Tcol + NN;              // NN
  float* pc   = Rcol + NN;              // NPB*KK*DD
  float* pw   = pc + NPB * KK * DD;     // NPB*16

  k1_split<<<NN, 256, 0, stream>>>(
      x, w1, b1, g1, be1, w2, b2, g2, be2, w3, b3, cw1, cb1,
      out_logits, out_probs, hi, hjbT, Srow, Qrow, Tcol, Rcol);
  k_centers_part<<<NPB, 128, 0, stream>>>(x, out_probs, pc, pw);
  dim3 g3((NN + TJ - 1) / TJ, (NN + TI - 1) / TI);
  k_matrix<<<g3, 256, 0, stream>>>(hi, hjbT, Srow, Qrow, Tcol, Rcol,
                                   cg1, cbe1, cw2, cb2, out_mat);
  k_tail<<<KK + (EE + 255) / 256, 256, 0, stream>>>(pc, pw, prot, ei, out_mat,
                                                    out_cent, out_proto, out_scores);
}

// Round 9
// 57.153 us; speedup vs baseline: 1.1002x; 1.1002x over previous
//
#include <hip/hip_runtime.h>
#include <hip/hip_bf16.h>
#include <math.h>

#define NN 1000
#define DD 128
#define HH 128
#define H2 64
#define KK 10
#define EE 500000
#define LN_EPS 1e-5f

typedef float v2f __attribute__((ext_vector_type(2)));

// output offsets (floats)
#define OFF_LOGITS  0
#define OFF_PROBS   10000
#define OFF_SCORES  20000
#define OFF_MATRIX  520000
#define OFF_CENTERS 1520000
#define OFF_PROTO   1521280

// ===== Kernel 1: split proj blocks (0..999) + cluster blocks (1000..1499) ===
__global__ __launch_bounds__(256) void k1_split(
    const float* __restrict__ x,
    const float* __restrict__ w1, const float* __restrict__ b1,
    const float* __restrict__ g1, const float* __restrict__ be1,
    const float* __restrict__ w2, const float* __restrict__ b2,
    const float* __restrict__ g2, const float* __restrict__ be2,
    const float* __restrict__ w3, const float* __restrict__ b3,
    const float* __restrict__ cw1, const float* __restrict__ cb1,
    float* __restrict__ out_logits, float* __restrict__ out_probs,
    float* __restrict__ hi, float* __restrict__ hjbT,
    float* __restrict__ Srow, float* __restrict__ Qrow,
    float* __restrict__ Tcol, float* __restrict__ Rcol) {
  const int b = blockIdx.x;
  const int t = threadIdx.x;

  if (b < NN) {
    // ---------------- proj block: row n = b ----------------
    __shared__ float sx[DD];
    __shared__ float red[8];
    if (t < 32) *(float4*)&sx[4 * t] = *(const float4*)&x[b * DD + 4 * t];
    __syncthreads();

    float a0 = 0.f, a1 = 0.f, a2 = 0.f, a3 = 0.f;
    const float* wcol = (t < 128) ? (cw1 + t) : (cw1 + DD * HH + (t - 128));
#pragma unroll 8
    for (int d = 0; d < DD; d += 4) {
      const float4 xv = *(const float4*)&sx[d];
      a0 = fmaf(xv.x, wcol[(d + 0) * HH], a0);
      a1 = fmaf(xv.y, wcol[(d + 1) * HH], a1);
      a2 = fmaf(xv.z, wcol[(d + 2) * HH], a2);
      a3 = fmaf(xv.w, wcol[(d + 3) * HH], a3);
    }
    float acc = (a0 + a1) + (a2 + a3);
    if (t >= 128) acc += cb1[t - 128];
    if (t < 128) hi[b * HH + t] = acc;
    else         hjbT[(t - 128) * NN + b] = acc;

    float s = acc, q = acc * acc;
#pragma unroll
    for (int o = 1; o < 64; o <<= 1) {
      s += __shfl_xor(s, o, 64);
      q += __shfl_xor(q, o, 64);
    }
    const int wid = t >> 6;
    if ((t & 63) == 0) { red[wid * 2] = s; red[wid * 2 + 1] = q; }
    __syncthreads();
    if (t == 0)   { Srow[b] = red[0] + red[2]; Qrow[b] = red[1] + red[3]; }
    if (t == 128) { Tcol[b] = red[4] + red[6]; Rcol[b] = red[5] + red[7]; }
  } else {
    // ---------------- cluster block: rows r0, r0+1 ----------------
    __shared__ float sx2[2][DD];
    __shared__ float shh[2][HH];
    __shared__ float sh2[2][H2];
    __shared__ float redc[8];
    __shared__ float slg2[2][16];
    const int m = b - NN;
    const int r0 = 2 * m;
    if (t < 32)      *(float4*)&sx2[0][4 * t] = *(const float4*)&x[r0 * DD + 4 * t];
    else if (t < 64) *(float4*)&sx2[1][4 * (t - 32)] =
                         *(const float4*)&x[(r0 + 1) * DD + 4 * (t - 32)];
    __syncthreads();

    const int row = t >> 7;
    const int col = t & 127;

    // ---- layer 1 ----
    float a0 = 0.f, a1 = 0.f, a2 = 0.f, a3 = 0.f;
    const float* wc = w1 + col;
#pragma unroll 8
    for (int d = 0; d < DD; d += 4) {
      const float4 xv = *(const float4*)&sx2[row][d];
      a0 = fmaf(xv.x, wc[(d + 0) * HH], a0);
      a1 = fmaf(xv.y, wc[(d + 1) * HH], a1);
      a2 = fmaf(xv.z, wc[(d + 2) * HH], a2);
      a3 = fmaf(xv.w, wc[(d + 3) * HH], a3);
    }
    float acc = (a0 + a1) + (a2 + a3) + b1[col];
    {
      float s = acc, q = acc * acc;
#pragma unroll
      for (int o = 1; o < 64; o <<= 1) {
        s += __shfl_xor(s, o, 64);
        q += __shfl_xor(q, o, 64);
      }
      const int wid = t >> 6;
      if ((t & 63) == 0) { redc[wid * 2] = s; redc[wid * 2 + 1] = q; }
    }
    __syncthreads();
    {
      const float s = redc[4 * row] + redc[4 * row + 2];
      const float q = redc[4 * row + 1] + redc[4 * row + 3];
      const float mn = s * (1.0f / HH);
      const float var = q * (1.0f / HH) - mn * mn;
      const float rs = rsqrtf(var + LN_EPS);
      shh[row][col] = fmaxf(fmaf((acc - mn) * rs, g1[col], be1[col]), 0.0f);
    }
    __syncthreads();

    // ---- layer 2 ----
    if (t < 128) {
      const int rw = t >> 6, c2 = t & 63;
      float b0 = 0.f, b1_ = 0.f, b2_ = 0.f, b3_ = 0.f;
      const float* w2c = w2 + c2;
#pragma unroll 8
      for (int d = 0; d < HH; d += 4) {
        const float4 hv = *(const float4*)&shh[rw][d];
        b0 = fmaf(hv.x, w2c[(d + 0) * H2], b0);
        b1_ = fmaf(hv.y, w2c[(d + 1) * H2], b1_);
        b2_ = fmaf(hv.z, w2c[(d + 2) * H2], b2_);
        b3_ = fmaf(hv.w, w2c[(d + 3) * H2], b3_);
      }
      float av = (b0 + b1_) + (b2_ + b3_) + b2[c2];
      float s2 = av, q2 = av * av;
#pragma unroll
      for (int o = 1; o < 64; o <<= 1) {
        s2 += __shfl_xor(s2, o, 64);
        q2 += __shfl_xor(q2, o, 64);
      }
      const float m2 = s2 * (1.0f / H2);
      const float var2 = q2 * (1.0f / H2) - m2 * m2;
      const float rs2 = rsqrtf(var2 + LN_EPS);
      sh2[rw][c2] = fmaxf(fmaf((av - m2) * rs2, g2[c2], be2[c2]), 0.0f);
    }
    __syncthreads();

    // ---- layer 3 + softmax ----
    if (t < 32) {
      const int rw = t >> 4, k = t & 15;
      if (k < KK) {
        float a3_ = b3[k];
#pragma unroll
        for (int d = 0; d < H2; ++d) a3_ = fmaf(sh2[rw][d], w3[d * KK + k], a3_);
        out_logits[(r0 + rw) * KK + k] = a3_;
        slg2[rw][k] = a3_;
      }
    }
    __syncthreads();
    if (t < 32) {
      const int rw = t >> 4, k = t & 15;
      if (k < KK) {
        float mx = -1e30f;
#pragma unroll
        for (int i = 0; i < KK; ++i) mx = fmaxf(mx, slg2[rw][i]);
        float den = 0.0f;
#pragma unroll
        for (int i = 0; i < KK; ++i) den += expf(slg2[rw][i] - mx);
        out_probs[(r0 + rw) * KK + k] = expf(slg2[rw][k] - mx) / den;
      }
    }
  }
}

// ===== Kernel 2: matrix tiles (blocks 0..511) + center partials (512..574) ==
#define TI 32
#define TJ 64
#define SA_STR 130  // floats per A row
#define SB_STR 68   // floats per B h-row
#define NMAT 512    // 16 j-tiles x 32 i-tiles
#define NPB2 126    // 126 half-block partials (125 used + 1 zero)

__global__ __launch_bounds__(256) void k_mc(
    const float* __restrict__ hi, const float* __restrict__ hjbT,
    const float* __restrict__ Srow, const float* __restrict__ Qrow,
    const float* __restrict__ Tcol, const float* __restrict__ Rcol,
    const float* __restrict__ cg1, const float* __restrict__ cbe1,
    const float* __restrict__ cw2, const float* __restrict__ cb2,
    const float* __restrict__ x, const float* __restrict__ probs,
    float* __restrict__ out_mat, float* __restrict__ pc, float* __restrict__ pw) {
  const int t = threadIdx.x;
  if (blockIdx.x >= NMAT) {
    // -------- cluster-center partials: two 128-thread halves -------------
    __shared__ float sp[2][8 * 16];
    const int half = t >> 7;
    const int lane = t & 127;
    const int part = (blockIdx.x - NMAT) * 2 + half;   // 0..125
    const int n0 = part * 8;
    if (lane < 8 * KK) {
      const int nn = lane / KK, k = lane % KK;
      const int n = n0 + nn;
      sp[half][nn * 16 + k] = (n < NN) ? probs[n * KK + k] : 0.0f;
    }
    __syncthreads();
    float acc[KK];
#pragma unroll
    for (int k = 0; k < KK; ++k) acc[k] = 0.0f;
#pragma unroll
    for (int nn = 0; nn < 8; ++nn) {
      const int n = n0 + nn;
      const float xv = (n < NN) ? x[n * DD + lane] : 0.0f;
#pragma unroll
      for (int k = 0; k < KK; ++k) acc[k] = fmaf(sp[half][nn * 16 + k], xv, acc[k]);
    }
#pragma unroll
    for (int k = 0; k < KK; ++k) pc[part * (KK * DD) + k * DD + lane] = acc[k];
    if (lane < KK) {
      float s = 0.0f;
#pragma unroll
      for (int nn = 0; nn < 8; ++nn) s += sp[half][nn * 16 + lane];
      pw[part * 16 + lane] = s;
    }
    return;
  }

  // ---------------- matrix tile ----------------
  __shared__ float sa[TI * SA_STR];   // 16.6 KB
  __shared__ float sb[HH * SB_STR];   // 34.8 KB
  const int j0 = (blockIdx.x & 15) * TJ;
  const int i0 = (blockIdx.x >> 4) * TI;

  // stage A
#pragma unroll
  for (int it = 0; it < 4; ++it) {
    const int idx = it * 256 + t;
    const int r = idx >> 5, w = idx & 31;
    int gi = i0 + r; if (gi >= NN) gi = NN - 1;
    *(float4*)&sa[r * SA_STR + 4 * w] = *(const float4*)&hi[gi * HH + 4 * w];
  }
  // stage B
  {
    const int c = t & 63;
    const int hw = t >> 6;
    int gj = j0 + c; if (gj >= NN) gj = NN - 1;
#pragma unroll
    for (int hb = 0; hb < 32; ++hb) {
      const int h = hb * 4 + hw;
      sb[h * SB_STR + c] = hjbT[h * NN + gj];
    }
  }
  __syncthreads();

  const int tr = t >> 4, tc = t & 15;
  const int ia = 2 * tr;
  const int ja = 4 * tc;
  const int gi0 = i0 + ia;
  const int gj0 = j0 + ja;

  float Sr[2], Qr[2];
#pragma unroll
  for (int r = 0; r < 2; ++r) {
    const int gi = (gi0 + r < NN) ? gi0 + r : NN - 1;
    Sr[r] = Srow[gi]; Qr[r] = Qrow[gi];
  }
  v2f Tc2[2], Rc2[2];
#pragma unroll
  for (int p = 0; p < 2; ++p) {
    const int ca = (gj0 + 2 * p < NN) ? gj0 + 2 * p : NN - 1;
    const int cb_ = (gj0 + 2 * p + 1 < NN) ? gj0 + 2 * p + 1 : NN - 1;
    Tc2[p] = (v2f){Tcol[ca], Tcol[cb_]};
    Rc2[p] = (v2f){Rcol[ca], Rcol[cb_]};
  }

  // ---- pass 1: dot over h ----
  v2f dt[2][2];
#pragma unroll
  for (int r = 0; r < 2; ++r) { dt[r][0] = (v2f){0, 0}; dt[r][1] = (v2f){0, 0}; }

#pragma unroll 4
  for (int h = 0; h < HH; h += 2) {
    const v2f a0 = *(const v2f*)&sa[(ia + 0) * SA_STR + h];
    const v2f a1 = *(const v2f*)&sa[(ia + 1) * SA_STR + h];
    const float4 blo = *(const float4*)&sb[h * SB_STR + ja];
    const float4 bhi = *(const float4*)&sb[(h + 1) * SB_STR + ja];
    const v2f b0l = (v2f){blo.x, blo.y}, b1l = (v2f){blo.z, blo.w};
    const v2f b0h = (v2f){bhi.x, bhi.y}, b1h = (v2f){bhi.z, bhi.w};
    dt[0][0] += (v2f){a0.x, a0.x} * b0l + (v2f){a0.y, a0.y} * b0h;
    dt[0][1] += (v2f){a0.x, a0.x} * b1l + (v2f){a0.y, a0.y} * b1h;
    dt[1][0] += (v2f){a1.x, a1.x} * b0l + (v2f){a1.y, a1.y} * b0h;
    dt[1][1] += (v2f){a1.x, a1.x} * b1l + (v2f){a1.y, a1.y} * b1h;
  }

  const float inv = 1.0f / HH;
  v2f rrv[2][2], nmv[2][2];
#pragma unroll
  for (int r = 0; r < 2; ++r)
#pragma unroll
    for (int p = 0; p < 2; ++p) {
      const v2f mu = (Sr[r] + Tc2[p]) * inv;
      const v2f ev2 = (Qr[r] + Rc2[p] + 2.0f * dt[r][p]) * inv;
      const v2f var = ev2 - mu * mu;
      v2f rs;
      rs.x = rsqrtf(var.x + LN_EPS);
      rs.y = rsqrtf(var.y + LN_EPS);
      rrv[r][p] = rs;
      nmv[r][p] = -mu * rs;
    }

  // ---- pass 2 ----
  v2f cc[2][2];
#pragma unroll
  for (int r = 0; r < 2; ++r) { cc[r][0] = (v2f){0, 0}; cc[r][1] = (v2f){0, 0}; }
  const v2f vzero = (v2f){0.f, 0.f};

#pragma unroll 4
  for (int h = 0; h < HH; h += 2) {
    const v2f a0 = *(const v2f*)&sa[(ia + 0) * SA_STR + h];
    const v2f a1 = *(const v2f*)&sa[(ia + 1) * SA_STR + h];
    const float4 blo = *(const float4*)&sb[h * SB_STR + ja];
    const float4 bhi = *(const float4*)&sb[(h + 1) * SB_STR + ja];
    const float g0 = cg1[h], g1_ = cg1[h + 1];
    const float e0 = cbe1[h], e1 = cbe1[h + 1];
    const float w0 = cw2[h], w1_ = cw2[h + 1];
    const v2f b0l = (v2f){blo.x, blo.y}, b1l = (v2f){blo.z, blo.w};
    const v2f b0h = (v2f){bhi.x, bhi.y}, b1h = (v2f){bhi.z, bhi.w};
#pragma unroll
    for (int r = 0; r < 2; ++r) {
      const v2f ar = (r == 0) ? a0 : a1;
      const v2f axl = (v2f){ar.x, ar.x};
      const v2f axh = (v2f){ar.y, ar.y};
#pragma unroll
      for (int p = 0; p < 2; ++p) {
        const v2f bl = (p == 0) ? b0l : b1l;
        const v2f bh = (p == 0) ? b0h : b1h;
        v2f z = (axl + bl) * rrv[r][p] + nmv[r][p];
        z = z * (v2f){g0, g0} + (v2f){e0, e0};
        z = __builtin_elementwise_max(z, vzero);
        cc[r][p] += z * (v2f){w0, w0};
        z = (axh + bh) * rrv[r][p] + nmv[r][p];
        z = z * (v2f){g1_, g1_} + (v2f){e1, e1};
        z = __builtin_elementwise_max(z, vzero);
        cc[r][p] += z * (v2f){w1_, w1_};
      }
    }
  }

  const float cb = cb2[0];
  if (gj0 < NN) {
#pragma unroll
    for (int r = 0; r < 2; ++r) {
      const int gi = gi0 + r;
      if (gi < NN) {
        float4 o;
        o.x = tanhf(cc[r][0].x + cb);
        o.y = tanhf(cc[r][0].y + cb);
        o.z = tanhf(cc[r][1].x + cb);
        o.w = tanhf(cc[r][1].y + cb);
        *(float4*)&out_mat[gi * NN + gj0] = o;
      }
    }
  }
}

// ===== Kernel 3: tail — centers finalize (blocks 0-9) + edge gather ========
__global__ __launch_bounds__(256) void k_tail(
    const float* __restrict__ pc, const float* __restrict__ pw,
    const float* __restrict__ proto, const int* __restrict__ ei,
    const float* __restrict__ mat,
    float* __restrict__ out_centers, float* __restrict__ out_proto,
    float* __restrict__ out_scores) {
  const int b = blockIdx.x;
  const int t = threadIdx.x;
  if (b < KK) {
    __shared__ float sred[128];
    const int k = b;
    if (t < 128) sred[t] = (t < NPB2) ? pw[t * 16 + k] : 0.0f;
    __syncthreads();
    for (int o = 64; o > 0; o >>= 1) {
      if (t < o) sred[t] += sred[t + o];
      __syncthreads();
    }
    if (t < 128) {
      const float wsum = sred[0] + 1e-8f;
      float acc = 0.0f;
#pragma unroll 6
      for (int bb = 0; bb < NPB2; ++bb) acc += pc[bb * (KK * DD) + k * DD + t];
      out_centers[k * DD + t] = acc / wsum;
      out_proto[k * DD + t] = proto[k * DD + t];
    }
  } else {
    const int e = (b - KK) * 256 + t;
    if (e < EE) {
      const int r = ei[e];
      const int c = ei[EE + e];
      out_scores[e] = mat[r * NN + c];
    }
  }
}

extern "C" void kernel_launch(void* const* d_in, const int* in_sizes, int n_in,
                              void* d_out, int out_size, void* d_ws, size_t ws_size,
                              hipStream_t stream) {
  const float* x    = (const float*)d_in[0];
  const int*   ei   = (const int*)d_in[1];
  const float* w1   = (const float*)d_in[2];
  const float* b1   = (const float*)d_in[3];
  const float* g1   = (const float*)d_in[4];
  const float* be1  = (const float*)d_in[5];
  const float* w2   = (const float*)d_in[6];
  const float* b2   = (const float*)d_in[7];
  const float* g2   = (const float*)d_in[8];
  const float* be2  = (const float*)d_in[9];
  const float* w3   = (const float*)d_in[10];
  const float* b3   = (const float*)d_in[11];
  const float* cw1  = (const float*)d_in[12];
  const float* cb1  = (const float*)d_in[13];
  const float* cg1  = (const float*)d_in[14];
  const float* cbe1 = (const float*)d_in[15];
  const float* cw2  = (const float*)d_in[16];
  const float* cb2  = (const float*)d_in[17];
  const float* prot = (const float*)d_in[18];

  float* out        = (float*)d_out;
  float* out_logits = out + OFF_LOGITS;
  float* out_probs  = out + OFF_PROBS;
  float* out_scores = out + OFF_SCORES;
  float* out_mat    = out + OFF_MATRIX;
  float* out_cent   = out + OFF_CENTERS;
  float* out_proto  = out + OFF_PROTO;

  float* hi   = (float*)d_ws;           // NN*HH
  float* hjbT = hi + NN * HH;           // HH*NN
  float* Srow = hjbT + NN * HH;         // NN
  float* Qrow = Srow + NN;              // NN
  float* Tcol = Qrow + NN;              // NN
  float* Rcol = Tcol + NN;              // NN
  float* pc   = Rcol + NN;              // NPB2*KK*DD
  float* pw   = pc + NPB2 * KK * DD;    // NPB2*16

  k1_split<<<NN + NN / 2, 256, 0, stream>>>(
      x, w1, b1, g1, be1, w2, b2, g2, be2, w3, b3, cw1, cb1,
      out_logits, out_probs, hi, hjbT, Srow, Qrow, Tcol, Rcol);
  k_mc<<<NMAT + 63, 256, 0, stream>>>(hi, hjbT, Srow, Qrow, Tcol, Rcol,
                                      cg1, cbe1, cw2, cb2, x, out_probs,
                                      out_mat, pc, pw);
  k_tail<<<KK + (EE + 255) / 256, 256, 0, stream>>>(pc, pw, prot, ei, out_mat,
                                                    out_cent, out_proto, out_scores);
}

// Round 10
// 52.935 us; speedup vs baseline: 1.1878x; 1.0797x over previous
//
#include <hip/hip_runtime.h>
#include <hip/hip_bf16.h>
#include <math.h>

#define NN 1000
#define DD 128
#define HH 128
#define H2 64
#define KK 10
#define EE 500000
#define LN_EPS 1e-5f

typedef float v2f __attribute__((ext_vector_type(2)));

// output offsets (floats)
#define OFF_LOGITS  0
#define OFF_PROBS   10000
#define OFF_SCORES  20000
#define OFF_MATRIX  520000
#define OFF_CENTERS 1520000
#define OFF_PROTO   1521280

#define NPROJ 250   // 4-row proj blocks
#define NCLUS 500   // 2-row cluster blocks

// ===== Kernel 1: proj blocks (0..249, 4 rows) + cluster blocks (250..749) ==
__global__ __launch_bounds__(256) void k1_split(
    const float* __restrict__ x,
    const float* __restrict__ w1, const float* __restrict__ b1,
    const float* __restrict__ g1, const float* __restrict__ be1,
    const float* __restrict__ w2, const float* __restrict__ b2,
    const float* __restrict__ g2, const float* __restrict__ be2,
    const float* __restrict__ w3, const float* __restrict__ b3,
    const float* __restrict__ cw1, const float* __restrict__ cb1,
    float* __restrict__ out_logits, float* __restrict__ out_probs,
    float* __restrict__ hi, float* __restrict__ hjbT,
    float* __restrict__ Srow, float* __restrict__ Qrow,
    float* __restrict__ Tcol, float* __restrict__ Rcol) {
  const int b = blockIdx.x;
  const int t = threadIdx.x;

  if (b < NPROJ) {
    // ------ proj block: rows r0..r0+3; weight col load shared by 4 rows ----
    __shared__ float sx4[4][DD];
    __shared__ float red[32];
    const int r0 = 4 * b;
    if (t < 128) {
      const int rr = t >> 5, c4 = t & 31;
      *(float4*)&sx4[rr][4 * c4] = *(const float4*)&x[(r0 + rr) * DD + 4 * c4];
    }
    __syncthreads();

    const int col = t & 127;
    const float* wcol = (t < 128) ? (cw1 + col) : (cw1 + DD * HH + col);
    float a0 = 0.f, a1 = 0.f, a2 = 0.f, a3 = 0.f;
#pragma unroll 8
    for (int d = 0; d < DD; ++d) {
      const float w = wcol[d * HH];
      a0 = fmaf(sx4[0][d], w, a0);
      a1 = fmaf(sx4[1][d], w, a1);
      a2 = fmaf(sx4[2][d], w, a2);
      a3 = fmaf(sx4[3][d], w, a3);
    }
    if (t >= 128) {
      const float cb_ = cb1[col];
      a0 += cb_; a1 += cb_; a2 += cb_; a3 += cb_;
    }
    if (t < 128) {
      hi[(r0 + 0) * HH + col] = a0;
      hi[(r0 + 1) * HH + col] = a1;
      hi[(r0 + 2) * HH + col] = a2;
      hi[(r0 + 3) * HH + col] = a3;
    } else {
      *(float4*)&hjbT[col * NN + r0] = (float4){a0, a1, a2, a3};
    }
    // stats for 4 rows
    float s0 = a0, q0 = a0 * a0, s1 = a1, q1 = a1 * a1;
    float s2 = a2, q2 = a2 * a2, s3 = a3, q3 = a3 * a3;
#pragma unroll
    for (int o = 1; o < 64; o <<= 1) {
      s0 += __shfl_xor(s0, o, 64); q0 += __shfl_xor(q0, o, 64);
      s1 += __shfl_xor(s1, o, 64); q1 += __shfl_xor(q1, o, 64);
      s2 += __shfl_xor(s2, o, 64); q2 += __shfl_xor(q2, o, 64);
      s3 += __shfl_xor(s3, o, 64); q3 += __shfl_xor(q3, o, 64);
    }
    const int wid = t >> 6;
    if ((t & 63) == 0) {
      float* rw = &red[wid * 8];
      rw[0] = s0; rw[1] = q0; rw[2] = s1; rw[3] = q1;
      rw[4] = s2; rw[5] = q2; rw[6] = s3; rw[7] = q3;
    }
    __syncthreads();
    if (t == 0) {
#pragma unroll
      for (int r = 0; r < 4; ++r) {
        Srow[r0 + r] = red[r * 2] + red[8 + r * 2];
        Qrow[r0 + r] = red[r * 2 + 1] + red[8 + r * 2 + 1];
      }
    }
    if (t == 128) {
#pragma unroll
      for (int r = 0; r < 4; ++r) {
        Tcol[r0 + r] = red[16 + r * 2] + red[24 + r * 2];
        Rcol[r0 + r] = red[16 + r * 2 + 1] + red[24 + r * 2 + 1];
      }
    }
  } else {
    // ---------------- cluster block: rows r0, r0+1 ----------------
    __shared__ float sx2[2][DD];
    __shared__ float shh[2][HH];
    __shared__ float sh2[2][H2];
    __shared__ float redc[8];
    __shared__ float slg2[2][16];
    const int m = b - NPROJ;
    const int r0 = 2 * m;
    if (t < 32)      *(float4*)&sx2[0][4 * t] = *(const float4*)&x[r0 * DD + 4 * t];
    else if (t < 64) *(float4*)&sx2[1][4 * (t - 32)] =
                         *(const float4*)&x[(r0 + 1) * DD + 4 * (t - 32)];
    __syncthreads();

    const int row = t >> 7;
    const int col = t & 127;

    // ---- layer 1 ----
    float a0 = 0.f, a1 = 0.f, a2 = 0.f, a3 = 0.f;
    const float* wc = w1 + col;
#pragma unroll 8
    for (int d = 0; d < DD; d += 4) {
      const float4 xv = *(const float4*)&sx2[row][d];
      a0 = fmaf(xv.x, wc[(d + 0) * HH], a0);
      a1 = fmaf(xv.y, wc[(d + 1) * HH], a1);
      a2 = fmaf(xv.z, wc[(d + 2) * HH], a2);
      a3 = fmaf(xv.w, wc[(d + 3) * HH], a3);
    }
    float acc = (a0 + a1) + (a2 + a3) + b1[col];
    {
      float s = acc, q = acc * acc;
#pragma unroll
      for (int o = 1; o < 64; o <<= 1) {
        s += __shfl_xor(s, o, 64);
        q += __shfl_xor(q, o, 64);
      }
      const int wid = t >> 6;
      if ((t & 63) == 0) { redc[wid * 2] = s; redc[wid * 2 + 1] = q; }
    }
    __syncthreads();
    {
      const float s = redc[4 * row] + redc[4 * row + 2];
      const float q = redc[4 * row + 1] + redc[4 * row + 3];
      const float mn = s * (1.0f / HH);
      const float var = q * (1.0f / HH) - mn * mn;
      const float rs = rsqrtf(var + LN_EPS);
      shh[row][col] = fmaxf(fmaf((acc - mn) * rs, g1[col], be1[col]), 0.0f);
    }
    __syncthreads();

    // ---- layer 2 ----
    if (t < 128) {
      const int rw = t >> 6, c2 = t & 63;
      float b0 = 0.f, b1_ = 0.f, b2_ = 0.f, b3_ = 0.f;
      const float* w2c = w2 + c2;
#pragma unroll 8
      for (int d = 0; d < HH; d += 4) {
        const float4 hv = *(const float4*)&shh[rw][d];
        b0 = fmaf(hv.x, w2c[(d + 0) * H2], b0);
        b1_ = fmaf(hv.y, w2c[(d + 1) * H2], b1_);
        b2_ = fmaf(hv.z, w2c[(d + 2) * H2], b2_);
        b3_ = fmaf(hv.w, w2c[(d + 3) * H2], b3_);
      }
      float av = (b0 + b1_) + (b2_ + b3_) + b2[c2];
      float s2 = av, q2 = av * av;
#pragma unroll
      for (int o = 1; o < 64; o <<= 1) {
        s2 += __shfl_xor(s2, o, 64);
        q2 += __shfl_xor(q2, o, 64);
      }
      const float m2 = s2 * (1.0f / H2);
      const float var2 = q2 * (1.0f / H2) - m2 * m2;
      const float rs2 = rsqrtf(var2 + LN_EPS);
      sh2[rw][c2] = fmaxf(fmaf((av - m2) * rs2, g2[c2], be2[c2]), 0.0f);
    }
    __syncthreads();

    // ---- layer 3 + softmax ----
    if (t < 32) {
      const int rw = t >> 4, k = t & 15;
      if (k < KK) {
        float a3_ = b3[k];
#pragma unroll
        for (int d = 0; d < H2; ++d) a3_ = fmaf(sh2[rw][d], w3[d * KK + k], a3_);
        out_logits[(r0 + rw) * KK + k] = a3_;
        slg2[rw][k] = a3_;
      }
    }
    __syncthreads();
    if (t < 32) {
      const int rw = t >> 4, k = t & 15;
      if (k < KK) {
        float mx = -1e30f;
#pragma unroll
        for (int i = 0; i < KK; ++i) mx = fmaxf(mx, slg2[rw][i]);
        float den = 0.0f;
#pragma unroll
        for (int i = 0; i < KK; ++i) den += expf(slg2[rw][i] - mx);
        out_probs[(r0 + rw) * KK + k] = expf(slg2[rw][k] - mx) / den;
      }
    }
  }
}

// ===== Kernel 2: matrix tiles (blocks 0..511) + center partials (512..574) ==
#define TI 32
#define TJ 64
#define SA_STR 130  // floats per A row
#define SB_STR 68   // floats per B h-row
#define NMAT 512    // 16 j-tiles x 32 i-tiles
#define NPB2 126    // 126 half-block partials (125 used + 1 zero)

__global__ __launch_bounds__(256) void k_mc(
    const float* __restrict__ hi, const float* __restrict__ hjbT,
    const float* __restrict__ Srow, const float* __restrict__ Qrow,
    const float* __restrict__ Tcol, const float* __restrict__ Rcol,
    const float* __restrict__ cg1, const float* __restrict__ cbe1,
    const float* __restrict__ cw2, const float* __restrict__ cb2,
    const float* __restrict__ x, const float* __restrict__ probs,
    float* __restrict__ out_mat, float* __restrict__ pc, float* __restrict__ pw) {
  const int t = threadIdx.x;
  if (blockIdx.x >= NMAT) {
    // -------- cluster-center partials: two 128-thread halves -------------
    __shared__ float sp[2][8 * 16];
    const int half = t >> 7;
    const int lane = t & 127;
    const int part = (blockIdx.x - NMAT) * 2 + half;   // 0..125
    const int n0 = part * 8;
    if (lane < 8 * KK) {
      const int nn = lane / KK, k = lane % KK;
      const int n = n0 + nn;
      sp[half][nn * 16 + k] = (n < NN) ? probs[n * KK + k] : 0.0f;
    }
    __syncthreads();
    float acc[KK];
#pragma unroll
    for (int k = 0; k < KK; ++k) acc[k] = 0.0f;
#pragma unroll
    for (int nn = 0; nn < 8; ++nn) {
      const int n = n0 + nn;
      const float xv = (n < NN) ? x[n * DD + lane] : 0.0f;
#pragma unroll
      for (int k = 0; k < KK; ++k) acc[k] = fmaf(sp[half][nn * 16 + k], xv, acc[k]);
    }
#pragma unroll
    for (int k = 0; k < KK; ++k) pc[part * (KK * DD) + k * DD + lane] = acc[k];
    if (lane < KK) {
      float s = 0.0f;
#pragma unroll
      for (int nn = 0; nn < 8; ++nn) s += sp[half][nn * 16 + lane];
      pw[part * 16 + lane] = s;
    }
    return;
  }

  // ---------------- matrix tile ----------------
  __shared__ float sa[TI * SA_STR];   // 16.6 KB
  __shared__ float sb[HH * SB_STR];   // 34.8 KB
  const int j0 = (blockIdx.x & 15) * TJ;
  const int i0 = (blockIdx.x >> 4) * TI;

  // stage A
#pragma unroll
  for (int it = 0; it < 4; ++it) {
    const int idx = it * 256 + t;
    const int r = idx >> 5, w = idx & 31;
    int gi = i0 + r; if (gi >= NN) gi = NN - 1;
    *(float4*)&sa[r * SA_STR + 4 * w] = *(const float4*)&hi[gi * HH + 4 * w];
  }
  // stage B
  {
    const int c = t & 63;
    const int hw = t >> 6;
    int gj = j0 + c; if (gj >= NN) gj = NN - 1;
#pragma unroll
    for (int hb = 0; hb < 32; ++hb) {
      const int h = hb * 4 + hw;
      sb[h * SB_STR + c] = hjbT[h * NN + gj];
    }
  }
  __syncthreads();

  const int tr = t >> 4, tc = t & 15;
  const int ia = 2 * tr;
  const int ja = 4 * tc;
  const int gi0 = i0 + ia;
  const int gj0 = j0 + ja;

  float Sr[2], Qr[2];
#pragma unroll
  for (int r = 0; r < 2; ++r) {
    const int gi = (gi0 + r < NN) ? gi0 + r : NN - 1;
    Sr[r] = Srow[gi]; Qr[r] = Qrow[gi];
  }
  v2f Tc2[2], Rc2[2];
#pragma unroll
  for (int p = 0; p < 2; ++p) {
    const int ca = (gj0 + 2 * p < NN) ? gj0 + 2 * p : NN - 1;
    const int cb_ = (gj0 + 2 * p + 1 < NN) ? gj0 + 2 * p + 1 : NN - 1;
    Tc2[p] = (v2f){Tcol[ca], Tcol[cb_]};
    Rc2[p] = (v2f){Rcol[ca], Rcol[cb_]};
  }

  // ---- pass 1: dot over h ----
  v2f dt[2][2];
#pragma unroll
  for (int r = 0; r < 2; ++r) { dt[r][0] = (v2f){0, 0}; dt[r][1] = (v2f){0, 0}; }

#pragma unroll 4
  for (int h = 0; h < HH; h += 2) {
    const v2f a0 = *(const v2f*)&sa[(ia + 0) * SA_STR + h];
    const v2f a1 = *(const v2f*)&sa[(ia + 1) * SA_STR + h];
    const float4 blo = *(const float4*)&sb[h * SB_STR + ja];
    const float4 bhi = *(const float4*)&sb[(h + 1) * SB_STR + ja];
    const v2f b0l = (v2f){blo.x, blo.y}, b1l = (v2f){blo.z, blo.w};
    const v2f b0h = (v2f){bhi.x, bhi.y}, b1h = (v2f){bhi.z, bhi.w};
    dt[0][0] += (v2f){a0.x, a0.x} * b0l + (v2f){a0.y, a0.y} * b0h;
    dt[0][1] += (v2f){a0.x, a0.x} * b1l + (v2f){a0.y, a0.y} * b1h;
    dt[1][0] += (v2f){a1.x, a1.x} * b0l + (v2f){a1.y, a1.y} * b0h;
    dt[1][1] += (v2f){a1.x, a1.x} * b1l + (v2f){a1.y, a1.y} * b1h;
  }

  const float inv = 1.0f / HH;
  v2f rrv[2][2], nmv[2][2];
#pragma unroll
  for (int r = 0; r < 2; ++r)
#pragma unroll
    for (int p = 0; p < 2; ++p) {
      const v2f mu = (Sr[r] + Tc2[p]) * inv;
      const v2f ev2 = (Qr[r] + Rc2[p] + 2.0f * dt[r][p]) * inv;
      const v2f var = ev2 - mu * mu;
      v2f rs;
      rs.x = rsqrtf(var.x + LN_EPS);
      rs.y = rsqrtf(var.y + LN_EPS);
      rrv[r][p] = rs;
      nmv[r][p] = -mu * rs;
    }

  // ---- pass 2 ----
  v2f cc[2][2];
#pragma unroll
  for (int r = 0; r < 2; ++r) { cc[r][0] = (v2f){0, 0}; cc[r][1] = (v2f){0, 0}; }
  const v2f vzero = (v2f){0.f, 0.f};

#pragma unroll 4
  for (int h = 0; h < HH; h += 2) {
    const v2f a0 = *(const v2f*)&sa[(ia + 0) * SA_STR + h];
    const v2f a1 = *(const v2f*)&sa[(ia + 1) * SA_STR + h];
    const float4 blo = *(const float4*)&sb[h * SB_STR + ja];
    const float4 bhi = *(const float4*)&sb[(h + 1) * SB_STR + ja];
    const float g0 = cg1[h], g1_ = cg1[h + 1];
    const float e0 = cbe1[h], e1 = cbe1[h + 1];
    const float w0 = cw2[h], w1_ = cw2[h + 1];
    const v2f b0l = (v2f){blo.x, blo.y}, b1l = (v2f){blo.z, blo.w};
    const v2f b0h = (v2f){bhi.x, bhi.y}, b1h = (v2f){bhi.z, bhi.w};
#pragma unroll
    for (int r = 0; r < 2; ++r) {
      const v2f ar = (r == 0) ? a0 : a1;
      const v2f axl = (v2f){ar.x, ar.x};
      const v2f axh = (v2f){ar.y, ar.y};
#pragma unroll
      for (int p = 0; p < 2; ++p) {
        const v2f bl = (p == 0) ? b0l : b1l;
        const v2f bh = (p == 0) ? b0h : b1h;
        v2f z = (axl + bl) * rrv[r][p] + nmv[r][p];
        z = z * (v2f){g0, g0} + (v2f){e0, e0};
        z = __builtin_elementwise_max(z, vzero);
        cc[r][p] += z * (v2f){w0, w0};
        z = (axh + bh) * rrv[r][p] + nmv[r][p];
        z = z * (v2f){g1_, g1_} + (v2f){e1, e1};
        z = __builtin_elementwise_max(z, vzero);
        cc[r][p] += z * (v2f){w1_, w1_};
      }
    }
  }

  const float cb = cb2[0];
  if (gj0 < NN) {
#pragma unroll
    for (int r = 0; r < 2; ++r) {
      const int gi = gi0 + r;
      if (gi < NN) {
        float4 o;
        o.x = tanhf(cc[r][0].x + cb);
        o.y = tanhf(cc[r][0].y + cb);
        o.z = tanhf(cc[r][1].x + cb);
        o.w = tanhf(cc[r][1].y + cb);
        *(float4*)&out_mat[gi * NN + gj0] = o;
      }
    }
  }
}

// ===== Kernel 3: tail — centers finalize (0-9) + edge gather (4/thread) ====
#define EPB 1024   // edges per block (256 thr x 4)
#define NEB 489    // ceil(500000/1024)

__global__ __launch_bounds__(256) void k_tail(
    const float* __restrict__ pc, const float* __restrict__ pw,
    const float* __restrict__ proto, const int* __restrict__ ei,
    const float* __restrict__ mat,
    float* __restrict__ out_centers, float* __restrict__ out_proto,
    float* __restrict__ out_scores) {
  const int b = blockIdx.x;
  const int t = threadIdx.x;
  if (b < KK) {
    __shared__ float sred[128];
    const int k = b;
    if (t < 128) sred[t] = (t < NPB2) ? pw[t * 16 + k] : 0.0f;
    __syncthreads();
    for (int o = 64; o > 0; o >>= 1) {
      if (t < o) sred[t] += sred[t + o];
      __syncthreads();
    }
    if (t < 128) {
      const float wsum = sred[0] + 1e-8f;
      float acc = 0.0f;
#pragma unroll 6
      for (int bb = 0; bb < NPB2; ++bb) acc += pc[bb * (KK * DD) + k * DD + t];
      out_centers[k * DD + t] = acc / wsum;
      out_proto[k * DD + t] = proto[k * DD + t];
    }
  } else {
    const int e = (b - KK) * EPB + 4 * t;
    if (e + 3 < EE) {
      const int4 r4 = *(const int4*)&ei[e];
      const int4 c4 = *(const int4*)&ei[EE + e];
      float4 o;
      o.x = mat[r4.x * NN + c4.x];
      o.y = mat[r4.y * NN + c4.y];
      o.z = mat[r4.z * NN + c4.z];
      o.w = mat[r4.w * NN + c4.w];
      *(float4*)&out_scores[e] = o;
    } else {
      for (int q = e; q < EE; ++q)
        out_scores[q] = mat[ei[q] * NN + ei[EE + q]];
    }
  }
}

extern "C" void kernel_launch(void* const* d_in, const int* in_sizes, int n_in,
                              void* d_out, int out_size, void* d_ws, size_t ws_size,
                              hipStream_t stream) {
  const float* x    = (const float*)d_in[0];
  const int*   ei   = (const int*)d_in[1];
  const float* w1   = (const float*)d_in[2];
  const float* b1   = (const float*)d_in[3];
  const float* g1   = (const float*)d_in[4];
  const float* be1  = (const float*)d_in[5];
  const float* w2   = (const float*)d_in[6];
  const float* b2   = (const float*)d_in[7];
  const float* g2   = (const float*)d_in[8];
  const float* be2  = (const float*)d_in[9];
  const float* w3   = (const float*)d_in[10];
  const float* b3   = (const float*)d_in[11];
  const float* cw1  = (const float*)d_in[12];
  const float* cb1  = (const float*)d_in[13];
  const float* cg1  = (const float*)d_in[14];
  const float* cbe1 = (const float*)d_in[15];
  const float* cw2  = (const float*)d_in[16];
  const float* cb2  = (const float*)d_in[17];
  const float* prot = (const float*)d_in[18];

  float* out        = (float*)d_out;
  float* out_logits = out + OFF_LOGITS;
  float* out_probs  = out + OFF_PROBS;
  float* out_scores = out + OFF_SCORES;
  float* out_mat    = out + OFF_MATRIX;
  float* out_cent   = out + OFF_CENTERS;
  float* out_proto  = out + OFF_PROTO;

  float* hi   = (float*)d_ws;           // NN*HH
  float* hjbT = hi + NN * HH;           // HH*NN
  float* Srow = hjbT + NN * HH;         // NN
  float* Qrow = Srow + NN;              // NN
  float* Tcol = Qrow + NN;              // NN
  float* Rcol = Tcol + NN;              // NN
  float* pc   = Rcol + NN;              // NPB2*KK*DD
  float* pw   = pc + NPB2 * KK * DD;    // NPB2*16

  k1_split<<<NPROJ + NCLUS, 256, 0, stream>>>(
      x, w1, b1, g1, be1, w2, b2, g2, be2, w3, b3, cw1, cb1,
      out_logits, out_probs, hi, hjbT, Srow, Qrow, Tcol, Rcol);
  k_mc<<<NMAT + 63, 256, 0, stream>>>(hi, hjbT, Srow, Qrow, Tcol, Rcol,
                                      cg1, cbe1, cw2, cb2, x, out_probs,
                                      out_mat, pc, pw);
  k_tail<<<KK + NEB, 256, 0, stream>>>(pc, pw, prot, ei, out_mat,
                                       out_cent, out_proto, out_scores);
}